// Round 2
// baseline (11283.086 us; speedup 1.0000x reference)
//
#include <hip/hip_runtime.h>
#include <cstddef>

// ---------------------------------------------------------------------------
// VQ-VAE forward, f32, batch-chunked pipeline sized to ws_size at runtime.
// Encoder must stay f32: VQ argmin flips (bf16 noise) would exceed absmax.
// ---------------------------------------------------------------------------

// Conv2d k=4 s=2 p=1 + optional ReLU. Thread computes G consecutive output
// channels at one output pixel. blockIdx.y = b*(Cout/G)+cg (wave-uniform ->
// scalar weight loads).
template<int CIN, int G, int RELU>
__global__ __launch_bounds__(256) void conv_k(
    const float* __restrict__ in, const float* __restrict__ wt,
    const float* __restrict__ bias, float* __restrict__ out,
    int Cout, int Hin, int Win) {
  const int Hout = Hin >> 1, Wout = Win >> 1;
  int hw = blockIdx.x * 256 + threadIdx.x;
  int oy = hw / Wout, ox = hw - oy * Wout;
  int cg = blockIdx.y % (Cout / G);
  int b  = blockIdx.y / (Cout / G);
  int co0 = cg * G;
  const int iy0 = 2 * oy - 1, ix0 = 2 * ox - 1;
  const float* ip = in + (size_t)b * CIN * Hin * Win;
  float acc[G];
#pragma unroll
  for (int j = 0; j < G; ++j) acc[j] = bias[co0 + j];
  const float* wbase = wt + (size_t)co0 * CIN * 16;
  for (int ci = 0; ci < CIN; ++ci) {
    const float* ic = ip + (size_t)ci * Hin * Win;
    float xv[16];
#pragma unroll
    for (int kh = 0; kh < 4; ++kh) {
      int iy = iy0 + kh;
      bool rok = (unsigned)iy < (unsigned)Hin;
      const float* row = ic + (ptrdiff_t)iy * Win;
#pragma unroll
      for (int kw = 0; kw < 4; ++kw) {
        int ix = ix0 + kw;
        xv[kh * 4 + kw] = (rok && (unsigned)ix < (unsigned)Win) ? row[ix] : 0.0f;
      }
    }
    const float* wc = wbase + ci * 16;
#pragma unroll
    for (int j = 0; j < G; ++j) {
      const float* wj = wc + (size_t)j * CIN * 16;
#pragma unroll
      for (int t2 = 0; t2 < 16; ++t2) acc[j] = fmaf(xv[t2], wj[t2], acc[j]);
    }
  }
  if (RELU) {
#pragma unroll
    for (int j = 0; j < G; ++j) acc[j] = fmaxf(acc[j], 0.0f);
  }
  size_t cs = (size_t)Hout * Wout;
  float* op = out + ((size_t)(b * Cout + co0) * Hout + oy) * Wout + ox;
#pragma unroll
  for (int j = 0; j < G; ++j) op[(size_t)j * cs] = acc[j];
}

// 1x1 conv (pre-VQ), no activation.
template<int CIN, int G>
__global__ __launch_bounds__(256) void conv1x1_k(
    const float* __restrict__ in, const float* __restrict__ wt,
    const float* __restrict__ bias, float* __restrict__ out,
    int Cout, int HW) {
  int hw = blockIdx.x * 256 + threadIdx.x;
  int cg = blockIdx.y % (Cout / G);
  int b  = blockIdx.y / (Cout / G);
  int co0 = cg * G;
  const float* ip = in + (size_t)b * CIN * HW + hw;
  float acc[G];
#pragma unroll
  for (int j = 0; j < G; ++j) acc[j] = bias[co0 + j];
  for (int ci = 0; ci < CIN; ++ci) {
    float xv = ip[(size_t)ci * HW];
#pragma unroll
    for (int j = 0; j < G; ++j)
      acc[j] = fmaf(xv, wt[(size_t)(co0 + j) * CIN + ci], acc[j]);
  }
  float* op = out + ((size_t)(b * Cout + co0)) * HW + hw;
#pragma unroll
  for (int j = 0; j < G; ++j) op[(size_t)j * HW] = acc[j];
}

// VQ nearest-neighbor: one thread per (b, n) vector of 64 dims.
// Codebook staged in LDS as float4, 4 chunks of 128 codes.
__global__ __launch_bounds__(128) void vq_k(
    const float* __restrict__ ze, const float* __restrict__ emb,
    float* __restrict__ zq, float* __restrict__ partial) {
  __shared__ float4 se4[128 * 16];   // 32 KB
  __shared__ float red[128];
  int tid = threadIdx.x;
  int gid = blockIdx.x * 128 + tid;
  int b = gid >> 10, n = gid & 1023;
  const float* zp = ze + ((size_t)b << 16) + n;   // z_e[b, d, n], d stride 1024
  float4 v4[16];
#pragma unroll
  for (int d = 0; d < 16; ++d) {
    v4[d].x = zp[(size_t)(4 * d + 0) << 10];
    v4[d].y = zp[(size_t)(4 * d + 1) << 10];
    v4[d].z = zp[(size_t)(4 * d + 2) << 10];
    v4[d].w = zp[(size_t)(4 * d + 3) << 10];
  }
  float best = 1e30f; int bi = 0;
  for (int c = 0; c < 4; ++c) {
    __syncthreads();
    for (int i = tid; i < 2048; i += 128)
      se4[i] = ((const float4*)emb)[(c << 11) + i];
    __syncthreads();
    for (int k = 0; k < 128; ++k) {
      const float4* e = se4 + (k << 4);
      float s = 0.0f;
#pragma unroll
      for (int d = 0; d < 16; ++d) {
        float4 ev = e[d];
        float t0 = v4[d].x - ev.x; s = fmaf(t0, t0, s);
        float t1 = v4[d].y - ev.y; s = fmaf(t1, t1, s);
        float t2 = v4[d].z - ev.z; s = fmaf(t2, t2, s);
        float t3 = v4[d].w - ev.w; s = fmaf(t3, t3, s);
      }
      if (s < best) { best = s; bi = (c << 7) + k; }   // strict < keeps first idx
    }
  }
  const float4* eb4 = (const float4*)emb + ((size_t)bi << 4);
  float* qp = zq + ((size_t)b << 16) + n;
  float ls = 0.0f;
#pragma unroll
  for (int d = 0; d < 16; ++d) {
    float4 q = eb4[d];
    qp[(size_t)(4 * d + 0) << 10] = q.x;
    qp[(size_t)(4 * d + 1) << 10] = q.y;
    qp[(size_t)(4 * d + 2) << 10] = q.z;
    qp[(size_t)(4 * d + 3) << 10] = q.w;
    float t0 = q.x - v4[d].x; ls = fmaf(t0, t0, ls);
    float t1 = q.y - v4[d].y; ls = fmaf(t1, t1, ls);
    float t2 = q.z - v4[d].z; ls = fmaf(t2, t2, ls);
    float t3 = q.w - v4[d].w; ls = fmaf(t3, t3, ls);
  }
  red[tid] = ls;
  __syncthreads();
  for (int s = 64; s > 0; s >>= 1) {
    if (tid < s) red[tid] += red[tid + s];
    __syncthreads();
  }
  if (tid == 0) partial[blockIdx.x] = red[0];
}

__global__ __launch_bounds__(256) void loss_fin(
    const float* __restrict__ partial, float* __restrict__ out) {
  __shared__ float red[256];
  int t = threadIdx.x;
  red[t] = partial[t];
  __syncthreads();
  for (int s = 128; s > 0; s >>= 1) {
    if (t < s) red[t] += red[t + s];
    __syncthreads();
  }
  if (t == 0) out[0] = red[0] * (2.0f / 2097152.0f);  // *2 / (32*1024*64)
}

// ConvTranspose2d k=4 s=2 p=1 (+ReLU or sigmoid). Parity decomposition:
// thread computes a 2x2 output block for G channels; all weights uniform.
template<int CIN, int G, int ACT>
__global__ __launch_bounds__(256) void convT_k(
    const float* __restrict__ in, const float* __restrict__ wt,
    const float* __restrict__ bias, float* __restrict__ out,
    int Cout, int Hin, int Win) {
  const int Hout = Hin * 2, Wout = Win * 2;
  int t = blockIdx.x * 256 + threadIdx.x;
  int ty = t / Win, tx = t - ty * Win;
  int og = blockIdx.y % (Cout / G);
  int b  = blockIdx.y / (Cout / G);
  int o0 = og * G;
  bool r0ok = ty >= 1, r2ok = (ty + 1) < Hin;
  bool c0ok = tx >= 1, c2ok = (tx + 1) < Win;
  const float* ip = in + (size_t)b * CIN * Hin * Win;
  float a00[G], a01[G], a10[G], a11[G];
#pragma unroll
  for (int j = 0; j < G; ++j) {
    float bb = bias[o0 + j];
    a00[j] = bb; a01[j] = bb; a10[j] = bb; a11[j] = bb;
  }
  for (int i = 0; i < CIN; ++i) {
    const float* ic = ip + (size_t)i * Hin * Win + (size_t)ty * Win + tx;
    float x00 = (r0ok && c0ok) ? ic[-Win - 1] : 0.0f;
    float x01 = r0ok           ? ic[-Win]     : 0.0f;
    float x02 = (r0ok && c2ok) ? ic[-Win + 1] : 0.0f;
    float x10 = c0ok           ? ic[-1]       : 0.0f;
    float x11 =                  ic[0];
    float x12 = c2ok           ? ic[1]        : 0.0f;
    float x20 = (r2ok && c0ok) ? ic[Win - 1]  : 0.0f;
    float x21 = r2ok           ? ic[Win]      : 0.0f;
    float x22 = (r2ok && c2ok) ? ic[Win + 1]  : 0.0f;
    const float* wv = wt + ((size_t)i * Cout + o0) * 16;
#pragma unroll
    for (int j = 0; j < G; ++j) {
      const float* w4 = wv + j * 16;
      a00[j] = fmaf(x11, w4[5],  fmaf(x10, w4[7],  fmaf(x01, w4[13], fmaf(x00, w4[15], a00[j]))));
      a01[j] = fmaf(x12, w4[4],  fmaf(x11, w4[6],  fmaf(x02, w4[12], fmaf(x01, w4[14], a01[j]))));
      a10[j] = fmaf(x21, w4[1],  fmaf(x20, w4[3],  fmaf(x11, w4[9],  fmaf(x10, w4[11], a10[j]))));
      a11[j] = fmaf(x22, w4[0],  fmaf(x21, w4[2],  fmaf(x12, w4[8],  fmaf(x11, w4[10], a11[j]))));
    }
  }
  size_t cs = (size_t)Hout * Wout;
  size_t base = ((size_t)(b * Cout + o0) * Hout + 2 * (size_t)ty) * Wout + 2 * tx;
#pragma unroll
  for (int j = 0; j < G; ++j) {
    float v00 = a00[j], v01 = a01[j], v10 = a10[j], v11 = a11[j];
    if (ACT == 1) {
      v00 = fmaxf(v00, 0.0f); v01 = fmaxf(v01, 0.0f);
      v10 = fmaxf(v10, 0.0f); v11 = fmaxf(v11, 0.0f);
    } else if (ACT == 2) {
      v00 = 1.0f / (1.0f + expf(-v00)); v01 = 1.0f / (1.0f + expf(-v01));
      v10 = 1.0f / (1.0f + expf(-v10)); v11 = 1.0f / (1.0f + expf(-v11));
    }
    *(float2*)(out + base + (size_t)j * cs)        = make_float2(v00, v01);
    *(float2*)(out + base + (size_t)j * cs + Wout) = make_float2(v10, v11);
  }
}

extern "C" void kernel_launch(void* const* d_in, const int* in_sizes, int n_in,
                              void* d_out, int out_size, void* d_ws, size_t ws_size,
                              hipStream_t stream) {
  const float* x   = (const float*)d_in[0];
  const float* ew1 = (const float*)d_in[1];
  const float* eb1 = (const float*)d_in[2];
  const float* ew2 = (const float*)d_in[3];
  const float* eb2 = (const float*)d_in[4];
  const float* ew3 = (const float*)d_in[5];
  const float* eb3 = (const float*)d_in[6];
  const float* pw  = (const float*)d_in[7];
  const float* pb  = (const float*)d_in[8];
  const float* emb = (const float*)d_in[9];
  const float* dw1 = (const float*)d_in[10];
  const float* db1 = (const float*)d_in[11];
  const float* dw2 = (const float*)d_in[12];
  const float* db2 = (const float*)d_in[13];
  const float* dw3 = (const float*)d_in[14];
  const float* db3 = (const float*)d_in[15];
  float* out = (float*)d_out;
  char* ws = (char*)d_ws;

  // Per-image byte sizes of pipeline tensors.
  //   h1: 128*128*128*4 = 8388608   h2: 256*64*64*4 = 4194304
  //   h3: 512*32*32*4   = 2097152   ze/zq: 64*32*32*4 = 262144 each
  // Region A = max(h1,h3,d2)=8388608/img, B = max(h2,d1)=4194304/img.
  // Per-image total = A+B+2*ze = 13107200 B. Chunk CB images at a time.
  const size_t PER = 13107200ull;
  int CB = 32;
  while (CB > 1 && (size_t)CB * PER + 1024ull > ws_size) CB >>= 1;
  const size_t SA = (size_t)CB * 8388608ull;
  const size_t SB = (size_t)CB * 4194304ull;
  const size_t SC = (size_t)CB * 262144ull;
  float* A    = (float*)(ws);
  float* Bp   = (float*)(ws + SA);
  float* ze   = (float*)(ws + SA + SB);
  float* zq   = (float*)(ws + SA + SB + SC);
  float* part = (float*)(ws + SA + SB + 2 * SC);   // 256 floats total

  for (int c0 = 0; c0 < 32; c0 += CB) {
    const float* xc = x + (size_t)c0 * 3 * 65536;
    float* outc = out + (size_t)c0 * 3 * 65536;
    // encoder: h1=A, h2=B, h3=A(reuse), ze, zq
    conv_k<3,   8, 1><<<dim3(64, CB * 16), 256, 0, stream>>>(xc, ew1, eb1, A,  128, 256, 256);
    conv_k<128, 8, 1><<<dim3(16, CB * 32), 256, 0, stream>>>(A,  ew2, eb2, Bp, 256, 128, 128);
    conv_k<256, 8, 1><<<dim3(4,  CB * 64), 256, 0, stream>>>(Bp, ew3, eb3, A,  512, 64,  64);
    conv1x1_k<512, 8><<<dim3(4,  CB * 8),  256, 0, stream>>>(A,  pw,  pb,  ze, 64, 1024);
    // VQ (8 partial entries per image -> 256 total across all chunks)
    vq_k<<<CB * 8, 128, 0, stream>>>(ze, emb, zq, part + (size_t)c0 * 8);
    // decoder: d1=B(reuse), d2=A(reuse)
    convT_k<64,  4, 1><<<dim3(4,  CB * 64), 256, 0, stream>>>(zq, dw1, db1, Bp, 256, 32,  32);
    convT_k<256, 4, 1><<<dim3(16, CB * 32), 256, 0, stream>>>(Bp, dw2, db2, A,  128, 64,  64);
    convT_k<128, 3, 2><<<dim3(64, CB * 1),  256, 0, stream>>>(A,  dw3, db3, outc, 3, 128, 128);
  }
  loss_fin<<<1, 256, 0, stream>>>(part, out + (size_t)(out_size - 1));
}

// Round 3
// 10324.129 us; speedup vs baseline: 1.0929x; 1.0929x over previous
//
#include <hip/hip_runtime.h>
#include <cstddef>

// ---------------------------------------------------------------------------
// VQ-VAE forward, f32, LDS-tiled convs. Batch-chunked to fit ws_size.
// Encoder stays f32: VQ argmin flips (bf16 noise) would exceed absmax.
// ---------------------------------------------------------------------------

// Conv2d k=4 s=2 p=1 (+ReLU), LDS-tiled. Block = 256 thr = 16x16 output tile,
// G output channels. Per ci: stage 34x34 input halo tile (pitch 35), then
// each thread reads its 4x4 window from LDS and FMAs against scalar weights.
template<int CIN, int G, int RELU>
__global__ __launch_bounds__(256) void conv_t(
    const float* __restrict__ in, const float* __restrict__ wt,
    const float* __restrict__ bias, float* __restrict__ out,
    int Cout, int Hin, int Win) {
  const int Hout = Hin >> 1, Wout = Win >> 1;
  const int TW = Wout >> 4;
  __shared__ float tile[34 * 35];
  int tid = threadIdx.x;
  int oxl = tid & 15, oyl = tid >> 4;
  int tyt = blockIdx.x / TW, txt = blockIdx.x - tyt * TW;
  int oy0 = tyt << 4, ox0 = txt << 4;
  int cg = blockIdx.y % (Cout / G);
  int b  = blockIdx.y / (Cout / G);
  int co0 = cg * G;
  const int iy_org = 2 * oy0 - 1, ix_org = 2 * ox0 - 1;
  const float* ip = in + (size_t)b * CIN * Hin * Win;
  float acc[G];
#pragma unroll
  for (int j = 0; j < G; ++j) acc[j] = bias[co0 + j];
  const int lbase = (2 * oyl) * 35 + 2 * oxl;
  for (int ci = 0; ci < CIN; ++ci) {
    const float* ic = ip + (size_t)ci * Hin * Win;
    __syncthreads();
#pragma unroll
    for (int k = 0; k < 5; ++k) {
      int idx = tid + k * 256;
      if (idx < 34 * 34) {
        int r = idx / 34, c = idx - r * 34;
        int iy = iy_org + r, ix = ix_org + c;
        float v = ((unsigned)iy < (unsigned)Hin && (unsigned)ix < (unsigned)Win)
                      ? ic[(size_t)iy * Win + ix] : 0.0f;
        tile[r * 35 + c] = v;
      }
    }
    __syncthreads();
    float xv[16];
#pragma unroll
    for (int kh = 0; kh < 4; ++kh)
#pragma unroll
      for (int kw = 0; kw < 4; ++kw)
        xv[kh * 4 + kw] = tile[lbase + kh * 35 + kw];
    const float* wc = wt + ((size_t)co0 * CIN + ci) * 16;
#pragma unroll
    for (int j = 0; j < G; ++j) {
      const float* wj = wc + (size_t)j * CIN * 16;
#pragma unroll
      for (int t2 = 0; t2 < 16; ++t2) acc[j] = fmaf(xv[t2], wj[t2], acc[j]);
    }
  }
  size_t cs = (size_t)Hout * Wout;
  float* op = out + ((size_t)(b * Cout + co0) * Hout + (oy0 + oyl)) * Wout + ox0 + oxl;
#pragma unroll
  for (int j = 0; j < G; ++j) {
    float v = acc[j];
    if (RELU) v = fmaxf(v, 0.0f);
    op[(size_t)j * cs] = v;
  }
}

// 1x1 conv (pre-VQ), no activation.
template<int CIN, int G>
__global__ __launch_bounds__(256) void conv1x1_k(
    const float* __restrict__ in, const float* __restrict__ wt,
    const float* __restrict__ bias, float* __restrict__ out,
    int Cout, int HW) {
  int hw = blockIdx.x * 256 + threadIdx.x;
  int cg = blockIdx.y % (Cout / G);
  int b  = blockIdx.y / (Cout / G);
  int co0 = cg * G;
  const float* ip = in + (size_t)b * CIN * HW + hw;
  float acc[G];
#pragma unroll
  for (int j = 0; j < G; ++j) acc[j] = bias[co0 + j];
#pragma unroll 4
  for (int ci = 0; ci < CIN; ++ci) {
    float xv = ip[(size_t)ci * HW];
#pragma unroll
    for (int j = 0; j < G; ++j)
      acc[j] = fmaf(xv, wt[(size_t)(co0 + j) * CIN + ci], acc[j]);
  }
  float* op = out + ((size_t)(b * Cout + co0)) * HW + hw;
#pragma unroll
  for (int j = 0; j < G; ++j) op[(size_t)j * HW] = acc[j];
}

// VQ nearest-neighbor: one thread per (b, n) vector of 64 dims.
__global__ __launch_bounds__(128) void vq_k(
    const float* __restrict__ ze, const float* __restrict__ emb,
    float* __restrict__ zq, float* __restrict__ partial) {
  __shared__ float4 se4[128 * 16];   // 32 KB
  __shared__ float red[128];
  int tid = threadIdx.x;
  int gid = blockIdx.x * 128 + tid;
  int b = gid >> 10, n = gid & 1023;
  const float* zp = ze + ((size_t)b << 16) + n;
  float4 v4[16];
#pragma unroll
  for (int d = 0; d < 16; ++d) {
    v4[d].x = zp[(size_t)(4 * d + 0) << 10];
    v4[d].y = zp[(size_t)(4 * d + 1) << 10];
    v4[d].z = zp[(size_t)(4 * d + 2) << 10];
    v4[d].w = zp[(size_t)(4 * d + 3) << 10];
  }
  float best = 1e30f; int bi = 0;
  for (int c = 0; c < 4; ++c) {
    __syncthreads();
    for (int i = tid; i < 2048; i += 128)
      se4[i] = ((const float4*)emb)[(c << 11) + i];
    __syncthreads();
    for (int k = 0; k < 128; ++k) {
      const float4* e = se4 + (k << 4);
      float s = 0.0f;
#pragma unroll
      for (int d = 0; d < 16; ++d) {
        float4 ev = e[d];
        float t0 = v4[d].x - ev.x; s = fmaf(t0, t0, s);
        float t1 = v4[d].y - ev.y; s = fmaf(t1, t1, s);
        float t2 = v4[d].z - ev.z; s = fmaf(t2, t2, s);
        float t3 = v4[d].w - ev.w; s = fmaf(t3, t3, s);
      }
      if (s < best) { best = s; bi = (c << 7) + k; }
    }
  }
  const float4* eb4 = (const float4*)emb + ((size_t)bi << 4);
  float* qp = zq + ((size_t)b << 16) + n;
  float ls = 0.0f;
#pragma unroll
  for (int d = 0; d < 16; ++d) {
    float4 q = eb4[d];
    qp[(size_t)(4 * d + 0) << 10] = q.x;
    qp[(size_t)(4 * d + 1) << 10] = q.y;
    qp[(size_t)(4 * d + 2) << 10] = q.z;
    qp[(size_t)(4 * d + 3) << 10] = q.w;
    float t0 = q.x - v4[d].x; ls = fmaf(t0, t0, ls);
    float t1 = q.y - v4[d].y; ls = fmaf(t1, t1, ls);
    float t2 = q.z - v4[d].z; ls = fmaf(t2, t2, ls);
    float t3 = q.w - v4[d].w; ls = fmaf(t3, t3, ls);
  }
  red[tid] = ls;
  __syncthreads();
  for (int s = 64; s > 0; s >>= 1) {
    if (tid < s) red[tid] += red[tid + s];
    __syncthreads();
  }
  if (tid == 0) partial[blockIdx.x] = red[0];
}

__global__ __launch_bounds__(256) void loss_fin(
    const float* __restrict__ partial, float* __restrict__ out) {
  __shared__ float red[256];
  int t = threadIdx.x;
  red[t] = partial[t];
  __syncthreads();
  for (int s = 128; s > 0; s >>= 1) {
    if (t < s) red[t] += red[t + s];
    __syncthreads();
  }
  if (t == 0) out[0] = red[0] * (2.0f / 2097152.0f);
}

// ConvTranspose2d k=4 s=2 p=1 (+ReLU/sigmoid), LDS-tiled. Block = 16x16 input
// positions; each thread produces a 2x2 output block for G channels.
// Per i: stage 18x18 halo tile (pitch 19), 9 LDS reads, 16*G FMAs.
template<int CIN, int G, int ACT>
__global__ __launch_bounds__(256) void convT_t(
    const float* __restrict__ in, const float* __restrict__ wt,
    const float* __restrict__ bias, float* __restrict__ out,
    int Cout, int Hin, int Win) {
  const int Hout = Hin * 2, Wout = Win * 2;
  const int TW = Win >> 4;
  __shared__ float tile[18 * 19];
  int tid = threadIdx.x;
  int txl = tid & 15, tyl = tid >> 4;
  int tyt = blockIdx.x / TW, txt = blockIdx.x - tyt * TW;
  int ty0 = tyt << 4, tx0 = txt << 4;
  int og = blockIdx.y % (Cout / G);
  int b  = blockIdx.y / (Cout / G);
  int o0 = og * G;
  const int iy_org = ty0 - 1, ix_org = tx0 - 1;
  const float* ip = in + (size_t)b * CIN * Hin * Win;
  float a00[G], a01[G], a10[G], a11[G];
#pragma unroll
  for (int j = 0; j < G; ++j) {
    float bb = bias[o0 + j];
    a00[j] = bb; a01[j] = bb; a10[j] = bb; a11[j] = bb;
  }
  const int lb = tyl * 19 + txl;
  for (int i = 0; i < CIN; ++i) {
    const float* ic = ip + (size_t)i * Hin * Win;
    __syncthreads();
#pragma unroll
    for (int k = 0; k < 2; ++k) {
      int idx = tid + k * 256;
      if (idx < 18 * 18) {
        int r = idx / 18, c = idx - r * 18;
        int iy = iy_org + r, ix = ix_org + c;
        float v = ((unsigned)iy < (unsigned)Hin && (unsigned)ix < (unsigned)Win)
                      ? ic[(size_t)iy * Win + ix] : 0.0f;
        tile[r * 19 + c] = v;
      }
    }
    __syncthreads();
    float x00 = tile[lb],          x01 = tile[lb + 1],      x02 = tile[lb + 2];
    float x10 = tile[lb + 19],     x11 = tile[lb + 20],     x12 = tile[lb + 21];
    float x20 = tile[lb + 38],     x21 = tile[lb + 39],     x22 = tile[lb + 40];
    const float* wv = wt + ((size_t)i * Cout + o0) * 16;
#pragma unroll
    for (int j = 0; j < G; ++j) {
      const float* w4 = wv + j * 16;
      a00[j] = fmaf(x11, w4[5],  fmaf(x10, w4[7],  fmaf(x01, w4[13], fmaf(x00, w4[15], a00[j]))));
      a01[j] = fmaf(x12, w4[4],  fmaf(x11, w4[6],  fmaf(x02, w4[12], fmaf(x01, w4[14], a01[j]))));
      a10[j] = fmaf(x21, w4[1],  fmaf(x20, w4[3],  fmaf(x11, w4[9],  fmaf(x10, w4[11], a10[j]))));
      a11[j] = fmaf(x22, w4[0],  fmaf(x21, w4[2],  fmaf(x12, w4[8],  fmaf(x11, w4[10], a11[j]))));
    }
  }
  size_t cs = (size_t)Hout * Wout;
  int ty = ty0 + tyl, tx = tx0 + txl;
  size_t base = ((size_t)(b * Cout + o0) * Hout + 2 * (size_t)ty) * Wout + 2 * tx;
#pragma unroll
  for (int j = 0; j < G; ++j) {
    float v00 = a00[j], v01 = a01[j], v10 = a10[j], v11 = a11[j];
    if (ACT == 1) {
      v00 = fmaxf(v00, 0.0f); v01 = fmaxf(v01, 0.0f);
      v10 = fmaxf(v10, 0.0f); v11 = fmaxf(v11, 0.0f);
    } else if (ACT == 2) {
      v00 = 1.0f / (1.0f + expf(-v00)); v01 = 1.0f / (1.0f + expf(-v01));
      v10 = 1.0f / (1.0f + expf(-v10)); v11 = 1.0f / (1.0f + expf(-v11));
    }
    *(float2*)(out + base + (size_t)j * cs)        = make_float2(v00, v01);
    *(float2*)(out + base + (size_t)j * cs + Wout) = make_float2(v10, v11);
  }
}

extern "C" void kernel_launch(void* const* d_in, const int* in_sizes, int n_in,
                              void* d_out, int out_size, void* d_ws, size_t ws_size,
                              hipStream_t stream) {
  const float* x   = (const float*)d_in[0];
  const float* ew1 = (const float*)d_in[1];
  const float* eb1 = (const float*)d_in[2];
  const float* ew2 = (const float*)d_in[3];
  const float* eb2 = (const float*)d_in[4];
  const float* ew3 = (const float*)d_in[5];
  const float* eb3 = (const float*)d_in[6];
  const float* pw  = (const float*)d_in[7];
  const float* pb  = (const float*)d_in[8];
  const float* emb = (const float*)d_in[9];
  const float* dw1 = (const float*)d_in[10];
  const float* db1 = (const float*)d_in[11];
  const float* dw2 = (const float*)d_in[12];
  const float* db2 = (const float*)d_in[13];
  const float* dw3 = (const float*)d_in[14];
  const float* db3 = (const float*)d_in[15];
  float* out = (float*)d_out;
  char* ws = (char*)d_ws;

  // Region A = max(h1,h3+?,d2)=8388608 B/img, B = max(h2,d1)=4194304 B/img,
  // ze/zq 262144 B/img each. Chunk CB images; CB sized to ws at runtime.
  const size_t PER = 13107200ull;
  int CB = 32;
  while (CB > 1 && (size_t)CB * PER + 1024ull > ws_size) CB >>= 1;
  const size_t SA = (size_t)CB * 8388608ull;
  const size_t SB = (size_t)CB * 4194304ull;
  const size_t SC = (size_t)CB * 262144ull;
  float* A    = (float*)(ws);
  float* Bp   = (float*)(ws + SA);
  float* ze   = (float*)(ws + SA + SB);
  float* zq   = (float*)(ws + SA + SB + SC);
  float* part = (float*)(ws + SA + SB + 2 * SC);   // 256 floats total

  for (int c0 = 0; c0 < 32; c0 += CB) {
    const float* xc = x + (size_t)c0 * 3 * 65536;
    float* outc = out + (size_t)c0 * 3 * 65536;
    // encoder
    conv_t<3,   16, 1><<<dim3(64, CB * 8),  256, 0, stream>>>(xc, ew1, eb1, A,  128, 256, 256);
    conv_t<128, 16, 1><<<dim3(16, CB * 16), 256, 0, stream>>>(A,  ew2, eb2, Bp, 256, 128, 128);
    conv_t<256, 16, 1><<<dim3(4,  CB * 32), 256, 0, stream>>>(Bp, ew3, eb3, A,  512, 64,  64);
    conv1x1_k<512, 4><<<dim3(4,  CB * 16), 256, 0, stream>>>(A,  pw,  pb,  ze, 64, 1024);
    // VQ
    vq_k<<<CB * 8, 128, 0, stream>>>(ze, emb, zq, part + (size_t)c0 * 8);
    // decoder
    convT_t<64,  8, 1><<<dim3(4,  CB * 32), 256, 0, stream>>>(zq, dw1, db1, Bp, 256, 32,  32);
    convT_t<256, 8, 1><<<dim3(16, CB * 16), 256, 0, stream>>>(Bp, dw2, db2, A,  128, 64,  64);
    convT_t<128, 3, 2><<<dim3(64, CB * 1),  256, 0, stream>>>(A,  dw3, db3, outc, 3, 128, 128);
  }
  loss_fin<<<1, 256, 0, stream>>>(part, out + (size_t)(out_size - 1));
}